// Round 7
// baseline (135.066 us; speedup 1.0000x reference)
//
#include <hip/hip_runtime.h>

// OESNN_SEPhIA_MultiTiled2: 32-step recurrent SNN, B=8192.
// R7: R6 geometry (32 lanes/batch-group, 2 groups/wave, 4096 waves = 4/SIMD)
// with the ENTIRE cross-lane float broadcast replaced by a 1-bit spike mask:
//   __ballot(m2A > th) -> 64-bit mask in SGPRs (free broadcast, no LDS pipe,
//   no lgkmcnt serialization). Layer-1 current is reconstructed as
//     cur1[o] = base1[o] + sum_{c spiking} d1c[o][c]
//   (algebraically equal to (I1e-I1o)*d1; base1/d1c are loop-invariant).
// Lanes 0-17 of each group: layer-0 channel c (36 W0 regs, pinned) + pw/m0
// stores. Lanes 18-25: layer-1 output o=l5-18 (base1 + 18 d1c regs, pinned)
// + s1/m1 stores. LDS usage: zero. spks0/mems0 numerics bit-identical to the
// passing R1-R6 kernels; spks1/mems1 differ only in benign summation order.

namespace {
constexpr int Tn = 32;
constexpr int Bn = 8192;
constexpr unsigned O_PW = 0;                        // spks0 (= pw0) [T,B,18]
constexpr unsigned O_S1 = Tn * Bn * 18;             // spks1 [T,B,8]
constexpr unsigned O_M0 = O_S1 + Tn * Bn * 8;       // mems0 [T,B,18]
constexpr unsigned O_M1 = O_M0 + Tn * Bn * 18;      // mems1 [T,B,8]
}

// Reference _allpass power values for spike=0/1 — exact op order used by all
// passing rounds.
__device__ __forceinline__ void sephia_pw(int c, const float* peakg,
                                          float& pon, float& poff) {
    const float wl    = 1550.0f + 0.8f * (float)c;
    const float halfw = 0.5f * (wl * 1e3f / 15000.0f);
    const float amp   = sqrtf((exp10f(peakg[c] / 10.0f) / 1000.0f) * 1e6f);
    const float lr0   = 0.1f * amp;
    const float a0    = sqrtf(lr0 * lr0);
    poff = a0 * a0;
    const float delta = -250.0f / halfw;
    const float den   = fmaf(delta, delta, 1.0f);
    const float qr    = fmaf(delta, delta, 0.1f) / den;
    const float qi    = (delta - 0.1f * delta) / den;
    const float lr = qr * amp, li = qi * amp;
    const float a  = sqrtf(fmaf(lr, lr, li * li));
    pon = a * a;
}

__global__ __launch_bounds__(256, 4)
void oesnn_kernel(const float* __restrict__ x_in,
                  const float* __restrict__ W0g,   // [2,18,18*2]
                  const float* __restrict__ d0g,   // [2,9]
                  const float* __restrict__ W1g,   // [1,18,16]
                  const float* __restrict__ d1g,   // [1,8]
                  const float* __restrict__ peakg, // [36]
                  float* __restrict__ out)
{
    const int wv   = threadIdx.x >> 6;           // wave in block (0..3)
    const int lane = threadIdx.x & 63;
    const int half = lane >> 5;                  // batch group in wave
    const int l5   = lane & 31;                  // lane in group
    const int b    = blockIdx.x * 8 + wv * 2 + half;

    const int  c  = (l5 < 18) ? l5 : 17;         // layer-0 channel (clamped)
    const int  tl = c / 9;
    const int  jc = c - 9 * tl;
    const int  o  = (l5 >= 18 && l5 < 26) ? (l5 - 18) : 0;  // layer-1 output
    const bool isL0   = l5 < 18;
    const bool isOut1 = (l5 >= 18) && (l5 < 26);

    // ---- layer-0 weights (36 floats), own-channel pw table ----
    float w0e[18], w0o[18];
    #pragma unroll
    for (int w = 0; w < 18; ++w) {
        const float2 p = *(const float2*)(W0g + (tl * 18 + w) * 18 + 2 * jc);
        w0e[w] = p.x;
        w0o[w] = p.y;
    }
    float dd0 = d0g[c];
    float pon, poff;
    sephia_pw(c, peakg, pon, poff);

    // ---- layer-1 constants: base1 (all-spikes-off) + per-channel deltas ----
    float dd1 = d1g[o];
    float base1, d1c[18];
    {
        float se_b = 0.f, so_b = 0.f;
        #pragma unroll
        for (int c2 = 0; c2 < 18; ++c2) {
            float pon2, poff2;
            sephia_pw(c2, peakg, pon2, poff2);
            const float w1e = W1g[c2 * 16 + 2 * o];
            const float w1o = W1g[c2 * 16 + 2 * o + 1];
            se_b = fmaf(poff2, w1e, se_b);
            so_b = fmaf(poff2, w1o, so_b);
            d1c[c2] = (pon2 - poff2) * (w1e - w1o) * dd1;
        }
        base1 = (se_b - so_b) * dd1;
    }

    // Pin all loop-invariant values so they cannot be remat'd into the loop.
    #pragma unroll
    for (int i = 0; i < 18; ++i) {
        asm volatile("" : "+v"(w0e[i]), "+v"(w0o[i]), "+v"(d1c[i]));
    }
    asm volatile("" : "+v"(dd0), "+v"(pon), "+v"(poff));
    asm volatile("" : "+v"(base1), "+v"(dd1));

    // ---- state & 32-bit element offsets ----
    float mem0 = 0.f, mem1 = 0.f;
    unsigned xoff  = (unsigned)b * 36 + (unsigned)tl * 18;
    unsigned opw_i = O_PW + (unsigned)b * 18 + (unsigned)c;
    unsigned om0_i = O_M0 + (unsigned)b * 18 + (unsigned)c;
    unsigned os1_i = O_S1 + (unsigned)b * 8 + (unsigned)o;
    unsigned om1_i = O_M1 + (unsigned)b * 8 + (unsigned)o;

    // prefetch t=0 (this tile's 18 floats = 9x float2, 8B aligned)
    float2 xv[9];
    {
        const float2* xp2 = (const float2*)(x_in + xoff);
        #pragma unroll
        for (int k = 0; k < 9; ++k) xv[k] = xp2[k];
    }

    const int shift = half * 32;

    #pragma unroll 2
    for (int t = 0; t < Tn; ++t) {
        // ---- layer 0: px = x*1e-4, se/so ascending-w fma chains ----
        float se = 0.f, so = 0.f;
        #pragma unroll
        for (int k = 0; k < 9; ++k) {
            const float p0 = xv[k].x * 1e-4f;
            const float p1 = xv[k].y * 1e-4f;
            se = fmaf(p0, w0e[2 * k],     se);
            so = fmaf(p0, w0o[2 * k],     so);
            se = fmaf(p1, w0e[2 * k + 1], se);
            so = fmaf(p1, w0o[2 * k + 1], so);
        }

        // xv consumed: prefetch next timestep
        xoff += Bn * 36;
        if (t < Tn - 1) {
            const float2* xp2 = (const float2*)(x_in + xoff);
            #pragma unroll
            for (int k = 0; k < 9; ++k) xv[k] = xp2[k];
        }

        // ---- balanced PD + LIF + MRR power ----
        const float c0  = (se - so) * dd0;
        const float m2A = (mem0 > 0.55f) ? 0.0f : fmaf(0.95f, mem0, c0);
        mem0 = m2A;
        const float pw  = (m2A > 0.55f) ? pon : poff;

        if (isL0) {
            out[opw_i] = pw;                     // 18+18 contiguous dwords/wave
            out[om0_i] = m2A;
        }

        // ---- spike mask broadcast: 1 bit/channel via ballot (no LDS) ----
        const unsigned long long bal = __ballot(m2A > 0.55f);
        const unsigned grp = (unsigned)(bal >> shift);   // this group's bits

        // ---- layer 1: cur1 = base1 + sum of spiking deltas ----
        float cur = base1;
        #pragma unroll
        for (int c2 = 0; c2 < 18; ++c2) {
            const float s = (float)((grp >> c2) & 1u);   // bfe + cvt
            cur = fmaf(s, d1c[c2], cur);
        }

        const float m2B = (mem1 > 0.25f) ? 0.0f : fmaf(0.95f, mem1, cur);
        mem1 = m2B;

        if (isOut1) {
            out[os1_i] = (m2B > 0.25f) ? 1.0f : 0.0f;    // 8+8 contiguous
            out[om1_i] = m2B;
        }

        opw_i += Bn * 18;
        om0_i += Bn * 18;
        os1_i += Bn * 8;
        om1_i += Bn * 8;
    }
}

extern "C" void kernel_launch(void* const* d_in, const int* in_sizes, int n_in,
                              void* d_out, int out_size, void* d_ws, size_t ws_size,
                              hipStream_t stream) {
    (void)in_sizes; (void)n_in; (void)out_size; (void)d_ws; (void)ws_size;
    const float* x  = (const float*)d_in[0];
    const float* W0 = (const float*)d_in[1];
    const float* d0 = (const float*)d_in[2];
    const float* W1 = (const float*)d_in[3];
    const float* d1 = (const float*)d_in[4];
    const float* pk = (const float*)d_in[5];
    float* out = (float*)d_out;

    dim3 grid(Bn / 8), block(256);   // 32 lanes/batch, 2 batches/wave
    hipLaunchKernelGGL(oesnn_kernel, grid, block, 0, stream,
                       x, W0, d0, W1, d1, pk, out);
}